// Round 12
// baseline (198.789 us; speedup 1.0000x reference)
//
#include <hip/hip_runtime.h>
#include <cfloat>
#include <cstdint>
#include <cstddef>

#define N_TOK 2048
#define D_MODEL 1024
#define N_HEAD 8
#define D_HEAD 64
#define N_BATCH 2
#define INNER_DIM 512

typedef __attribute__((ext_vector_type(4))) float f32x4;
typedef __bf16 bfv8 __attribute__((ext_vector_type(8)));

#define KEEPV(x) asm volatile("" : : "v"(x))

__device__ __forceinline__ short f2bf(float f) {
  union { float f; unsigned u; } x{f};
  unsigned r = (x.u + 0x7fffu + ((x.u >> 16) & 1u)) >> 16;
  return (short)r;
}
__device__ __forceinline__ float bf2f(short s) {
  union { unsigned u; float f; } x;
  x.u = ((unsigned)(unsigned short)s) << 16;
  return x.f;
}
__device__ __forceinline__ void gload_lds16(const void* g, void* l) {
  __builtin_amdgcn_global_load_lds(
      (const __attribute__((address_space(1))) void*)g,
      (__attribute__((address_space(3))) void*)l, 16, 0, 0);
}
__device__ __forceinline__ void gload_lds4(const void* g, void* l) {
  __builtin_amdgcn_global_load_lds(
      (const __attribute__((address_space(1))) void*)g,
      (__attribute__((address_space(3))) void*)l, 4, 0, 0);
}

// ---------------- LayerNorm + bf16 cast of both xn and x ----------------
__global__ __launch_bounds__(256) void ln_cast_kernel(
    const float* __restrict__ x, const float* __restrict__ gamma,
    short* __restrict__ xn, short* __restrict__ xb) {
  const int row = blockIdx.x;
  const int tid = threadIdx.x;
  const float4 v = ((const float4*)(x + (size_t)row * D_MODEL))[tid];
  float s = v.x + v.y + v.z + v.w;
  float s2 = v.x * v.x + v.y * v.y + v.z * v.z + v.w * v.w;
#pragma unroll
  for (int off = 1; off < 64; off <<= 1) {
    s += __shfl_xor(s, off);
    s2 += __shfl_xor(s2, off);
  }
  __shared__ float red[8];
  const int wid = tid >> 6;
  if ((tid & 63) == 0) { red[wid] = s; red[wid + 4] = s2; }
  __syncthreads();
  s = red[0] + red[1] + red[2] + red[3];
  s2 = red[4] + red[5] + red[6] + red[7];
  const float mu = s * (1.f / D_MODEL);
  const float var = s2 * (1.f / D_MODEL) - mu * mu;
  const float rstd = rsqrtf(var + 1e-5f);
  const float4 g = ((const float4*)gamma)[tid];
  short4 xnv, xbv;
  xnv.x = f2bf((v.x - mu) * rstd * g.x);
  xnv.y = f2bf((v.y - mu) * rstd * g.y);
  xnv.z = f2bf((v.z - mu) * rstd * g.z);
  xnv.w = f2bf((v.w - mu) * rstd * g.w);
  xbv.x = f2bf(v.x); xbv.y = f2bf(v.y); xbv.z = f2bf(v.z); xbv.w = f2bf(v.w);
  ((short4*)(xn + (size_t)row * D_MODEL))[tid] = xnv;
  ((short4*)(xb + (size_t)row * D_MODEL))[tid] = xbv;
}

// ---------------- weight cast + transpose: Wt[n][k] = bf16(W[k][n]) ----------------
__global__ __launch_bounds__(256) void wcast_t_kernel(
    const float* __restrict__ W, short* __restrict__ Wt, int K, int Nc) {
  __shared__ short t[64][65];
  const int n0 = blockIdx.x * 64, k0 = blockIdx.y * 64;
  const int tid = threadIdx.x;
#pragma unroll
  for (int i = 0; i < 16; ++i) {
    int lin = i * 256 + tid;
    int kr = lin >> 6, nc = lin & 63;
    t[nc][kr] = f2bf(W[(size_t)(k0 + kr) * Nc + n0 + nc]);
  }
  __syncthreads();
#pragma unroll
  for (int i = 0; i < 16; ++i) {
    int lin = i * 256 + tid;
    int nr = lin >> 6, kc = lin & 63;
    Wt[(size_t)(n0 + nr) * K + k0 + kc] = t[nr][kc];
  }
}

// ---------------- NT GEMM: C[M,N] = A[M,K] * Bt[N,K]^T, 128x128 tile ----------------
template <int EPI>
__global__ __launch_bounds__(256) void gemm_nt_kernel(
    const short* __restrict__ A, const short* __restrict__ Bt,
    void* __restrict__ C0, void* __restrict__ C1, int M, int N, int K) {
  __shared__ __align__(16) short As[128 * 64];
  __shared__ __align__(16) short Bs[128 * 64];
  const int tid = threadIdx.x;
  const int lane = tid & 63, wid = tid >> 6;
  const int l15 = lane & 15, l4 = lane >> 4;
  const int m0 = blockIdx.y * 128, n0 = blockIdx.x * 128;
  const int wr = (wid >> 1) * 64, wc = (wid & 1) * 64;
  f32x4 acc[4][4] = {};
  for (int k0 = 0; k0 < K; k0 += 64) {
#pragma unroll
    for (int it = 0; it < 4; ++it) {
      int c = it * 256 + tid;
      int r = c >> 3, cc = (c & 7) << 3;
      gload_lds16(A + (size_t)(m0 + r) * K + k0 + cc, As + (size_t)(it * 256 + wid * 64) * 8);
      gload_lds16(Bt + (size_t)(n0 + r) * K + k0 + cc, Bs + (size_t)(it * 256 + wid * 64) * 8);
    }
    __syncthreads();
#pragma unroll
    for (int kk = 0; kk < 2; ++kk) {
      bfv8 af[4], bfr[4];
#pragma unroll
      for (int i = 0; i < 4; ++i) {
        af[i] = *(const bfv8*)&As[(wr + i * 16 + l15) * 64 + kk * 32 + l4 * 8];
        bfr[i] = *(const bfv8*)&Bs[(wc + i * 16 + l15) * 64 + kk * 32 + l4 * 8];
      }
#pragma unroll
      for (int mi = 0; mi < 4; ++mi)
#pragma unroll
        for (int ni = 0; ni < 4; ++ni)
          acc[mi][ni] = __builtin_amdgcn_mfma_f32_16x16x32_bf16(af[mi], bfr[ni], acc[mi][ni], 0, 0, 0);
    }
    __syncthreads();
  }
#pragma unroll
  for (int mi = 0; mi < 4; ++mi) {
#pragma unroll
    for (int ni = 0; ni < 4; ++ni) {
#pragma unroll
      for (int r = 0; r < 4; ++r) {
        const int row = m0 + wr + mi * 16 + l4 * 4 + r;
        const int col = n0 + wc + ni * 16 + l15;
        const float v = acc[mi][ni][r];
        if (EPI == 0) {
          const int b = row >> 11, n = row & (N_TOK - 1);
          const int h = col >> 6, d = col & 63;
          ((short*)C0)[(((size_t)(b * N_HEAD + h)) * N_TOK + n) * D_HEAD + d] = f2bf(v * 0.125f);
        } else if (EPI == 1) {
          const int b = row >> 11, n = row & (N_TOK - 1);
          if (col < 64)
            ((short*)C0)[((size_t)b * N_TOK + n) * D_HEAD + col] = f2bf(v);
          else
            ((short*)C1)[((size_t)b * D_HEAD + (col - 64)) * N_TOK + n] = f2bf(v);
        } else {
          ((float*)C0)[(size_t)row * D_MODEL + col] = v;
        }
      }
    }
  }
}

// ---------------- column mean of V (for fully-masked rows) ----------------
__global__ __launch_bounds__(256) void vmean_kernel(const short* __restrict__ vt,
                                                    float* __restrict__ vm) {
  const int bd = blockIdx.x;  // b*64 + d
  const short* rowp = vt + (size_t)bd * N_TOK;
  const int tid = threadIdx.x;
  float s = 0.f;
  for (int i = tid; i < N_TOK; i += 256) s += bf2f(rowp[i]);
#pragma unroll
  for (int off = 1; off < 64; off <<= 1) s += __shfl_xor(s, off);
  __shared__ float red[4];
  if ((tid & 63) == 0) red[tid >> 6] = s;
  __syncthreads();
  if (tid == 0) vm[bd] = (red[0] + red[1] + red[2] + red[3]) * (1.f / N_TOK);
}

// ---------------- flash attention: batch-paired 2-wave blocks ----------------
// Block = (h, qw), 2 waves; wave w = batch w. Both share one bias LDS tile
// (bias is batch-independent). Bias double-buffered via global_load_lds
// (size 4; PER-LANE global source = row + lane, wave-uniform LDS base) ->
// unsinkable, no compiler vmcnt on consume. Body top does the ONLY vmcnt(0)
// (explicit asm; sole outstanding vmem = bias stage, issued a full softmax+PV
// window earlier) + raw s_barrier + compiler fence. mask/V loads pinned with
// empty asm AFTER QK so they can't sink below the stage.
__global__ __launch_bounds__(128, 2) void attn_kernel(
    const short* __restrict__ qg,   // [B*H, N, 64] bf16, pre-scaled
    const short* __restrict__ kg,   // [B, N, 64] bf16
    const short* __restrict__ vtg,  // [B, 64, N] bf16 (transposed V)
    const float* __restrict__ bias, // [H, N, N] fp32
    const int* __restrict__ mask,   // [B, N] int
    const float* __restrict__ vm,   // [B, 64] fp32
    short* __restrict__ og) {       // [B*N, 512] bf16
  const int h = blockIdx.x;             // 8 heads
  const int qw = 127 - (int)blockIdx.y; // heavy-first
  const int wid = threadIdx.x >> 6;     // wave id == batch
  const int b = wid;
  const int lane = threadIdx.x & 63;
  const int l15 = lane & 15, l4 = lane >> 4;

  // bias tile [16][132] f32 (132 = 128 + 4 pad -> 2-way banks on read),
  // double-buffered; staged as 64-float chunks (one gload_lds4 = 64 lanes x 4B).
  __shared__ __align__(16) float blds[2][16 * 132];
  __shared__ __align__(16) short plds2[2][1024];  // per-wave P staging
  short* plds = &plds2[wid][0];

  const int qrow0 = qw * 16;
  const short* qp = qg + (((size_t)(b * N_HEAD + h)) * N_TOK + qrow0 + l15) * D_HEAD + l4 * 8;
  const bfv8 qf0 = *(const bfv8*)qp;
  const bfv8 qf1 = *(const bfv8*)(qp + 32);
  const int i_base = qrow0 + l4 * 4;
  const int nt = qw / 8 + 1;  // 128-wide j-tiles

  f32x4 oacc[4] = {};
  float m_r[4], l_r[4];
#pragma unroll
  for (int r = 0; r < 4; ++r) { m_r[r] = -FLT_MAX; l_r[r] = 0.f; }

  const float* bias_q = bias + ((size_t)h * N_TOK + qrow0) * N_TOK;
  const int* mask_b = mask + b * N_TOK + l15;
  const int w8 = wid * 8;  // this wave stages rows [w8, w8+8)

  // stage bias tile jn into blds[buf]: 16 gload_lds4 per wave.
  // global source is PER-LANE (row + chunk + lane); LDS dest base is uniform,
  // HW writes lane l's value at base + 4*l.
#define STAGE_BIAS(JN, BUF)                                                            \
  _Pragma("unroll") for (int it = 0; it < 16; ++it) {                                  \
    const int sr = w8 + (it >> 1), sh = it & 1;                                        \
    gload_lds4(bias_q + (size_t)sr * N_TOK + (JN) + sh * 64 + lane,                    \
               &blds[BUF][sr * 132 + sh * 64]);                                        \
  }

  STAGE_BIAS(0, 0)  // prologue: tile 0 -> buf 0

  int cur = 0;
  for (int t = 0; t < nt; ++t) {
    // ---- body top: sole vmcnt wait (bias stage) + cross-wave sync ----
    asm volatile("s_waitcnt vmcnt(0)" ::: "memory");
    __builtin_amdgcn_s_barrier();
    asm volatile("" ::: "memory");  // compiler fence: no LDS motion across barrier
    __builtin_amdgcn_sched_barrier(0);

    const int j0 = t * 128;
    // ---- mask + V loads ----
    int mk[8];
#pragma unroll
    for (int mf = 0; mf < 8; ++mf) mk[mf] = mask_b[j0 + mf * 16];
    bfv8 vf[16];
    const short* vp = vtg + ((size_t)b * D_HEAD + l15) * N_TOK + j0 + l4 * 8;
#pragma unroll
    for (int hh = 0; hh < 2; ++hh)
#pragma unroll
      for (int ks = 0; ks < 2; ++ks)
#pragma unroll
        for (int df = 0; df < 4; ++df)
          vf[hh * 8 + ks * 4 + df] = *(const bfv8*)(vp + hh * 64 + df * (16 * N_TOK) + ks * 32);
    // ---- QK^T ----
    f32x4 s[8] = {};
    const short* kp = kg + ((size_t)b * N_TOK + j0 + l15) * D_HEAD + l4 * 8;
#pragma unroll
    for (int ks = 0; ks < 2; ++ks) {
      const bfv8 qf = ks ? qf1 : qf0;
#pragma unroll
      for (int mf = 0; mf < 8; ++mf) {
        const bfv8 kf = *(const bfv8*)(kp + mf * (16 * D_HEAD) + ks * 32);
        s[mf] = __builtin_amdgcn_mfma_f32_16x16x32_bf16(qf, kf, s[mf], 0, 0, 0);
      }
    }
    // pin mask/V issue above this point (so they're OLDER than the stage below)
#pragma unroll
    for (int mf = 0; mf < 8; ++mf) KEEPV(mk[mf]);
#pragma unroll
    for (int i = 0; i < 16; ++i) KEEPV(vf[i]);
    __builtin_amdgcn_sched_barrier(0);
    // ---- stage bias(t+1) -> other buffer (youngest vmem; nothing waits on it) ----
    {
      const int jn = (t + 1 < nt) ? (t + 1) * 128 : j0;
      STAGE_BIAS(jn, cur ^ 1)
    }
    __builtin_amdgcn_sched_barrier(0);
    // ---- softmax: bias(t) from blds[cur] ----
    const float* bc = &blds[cur][0];
    float rowmax[4] = {-FLT_MAX, -FLT_MAX, -FLT_MAX, -FLT_MAX};
#pragma unroll
    for (int mf = 0; mf < 8; ++mf) {
      const int j = j0 + mf * 16 + l15;
#pragma unroll
      for (int r = 0; r < 4; ++r) {
        float v = s[mf][r] + bc[(l4 * 4 + r) * 132 + mf * 16 + l15];
        const bool ok = (j <= i_base + r) && (mk[mf] != 0);
        v = ok ? v : -FLT_MAX;
        s[mf][r] = v;
        rowmax[r] = fmaxf(rowmax[r], v);
      }
    }
#pragma unroll
    for (int off = 1; off < 16; off <<= 1)
#pragma unroll
      for (int r = 0; r < 4; ++r)
        rowmax[r] = fmaxf(rowmax[r], __shfl_xor(rowmax[r], off));
    float alpha[4], rsum[4];
#pragma unroll
    for (int r = 0; r < 4; ++r) {
      const float mn = fmaxf(m_r[r], rowmax[r]);
      alpha[r] = __expf(m_r[r] - mn);
      m_r[r] = mn;
      float rs = 0.f;
#pragma unroll
      for (int mf = 0; mf < 8; ++mf) {
        const float e = __expf(s[mf][r] - mn);
        s[mf][r] = e;
        rs += e;
      }
      rsum[r] = rs;
    }
#pragma unroll
    for (int off = 1; off < 16; off <<= 1)
#pragma unroll
      for (int r = 0; r < 4; ++r) rsum[r] += __shfl_xor(rsum[r], off);
#pragma unroll
    for (int r = 0; r < 4; ++r) l_r[r] = l_r[r] * alpha[r] + rsum[r];
#pragma unroll
    for (int df = 0; df < 4; ++df)
#pragma unroll
      for (int r = 0; r < 4; ++r) oacc[df][r] *= alpha[r];
    // ---- P -> LDS (swizzled, per-wave), PV with pinned V regs ----
#pragma unroll
    for (int hh = 0; hh < 2; ++hh) {
#pragma unroll
      for (int nf = 0; nf < 4; ++nf) {
        const int ch = (nf * 16 + l15) >> 3;
        const int cl = l15 & 7;
#pragma unroll
        for (int r = 0; r < 4; ++r) {
          const int row = l4 * 4 + r;
          const int g = row * 8 + (ch ^ (row & 7));
          plds[g * 8 + cl] = f2bf(s[hh * 4 + nf][r]);
        }
      }
#pragma unroll
      for (int ks = 0; ks < 2; ++ks) {
        const int g = l15 * 8 + ((ks * 4 + l4) ^ (l15 & 7));
        const bfv8 pf = *(const bfv8*)&plds[g * 8];
#pragma unroll
        for (int df = 0; df < 4; ++df)
          oacc[df] = __builtin_amdgcn_mfma_f32_16x16x32_bf16(
              pf, vf[hh * 8 + ks * 4 + df], oacc[df], 0, 0, 0);
      }
    }
    cur ^= 1;
  }
#undef STAGE_BIAS

#pragma unroll
  for (int r = 0; r < 4; ++r) {
    const int i = i_base + r;
    const bool degen = (m_r[r] == -FLT_MAX);
    const float sc = degen ? 0.f : 1.f / l_r[r];
#pragma unroll
    for (int df = 0; df < 4; ++df) {
      const int d = df * 16 + l15;
      float v = oacc[df][r] * sc;
      if (degen) v = vm[b * D_HEAD + d];
      og[((size_t)b * N_TOK + i) * INNER_DIM + h * D_HEAD + d] = f2bf(v);
    }
  }
}

extern "C" void kernel_launch(void* const* d_in, const int* in_sizes, int n_in,
                              void* d_out, int out_size, void* d_ws, size_t ws_size,
                              hipStream_t stream) {
  const float* x = (const float*)d_in[0];
  const int* mask = (const int*)d_in[1];
  const float* bias = (const float*)d_in[2];
  const float* gamma = (const float*)d_in[3];
  const float* Wq = (const float*)d_in[4];
  const float* Wkv = (const float*)d_in[5];
  const float* Wo = (const float*)d_in[6];
  float* out = (float*)d_out;

  char* w = (char*)d_ws;
  short* xn = (short*)w;  w += (size_t)4096 * 1024 * 2;
  short* xb = (short*)w;  w += (size_t)4096 * 1024 * 2;
  short* wqt = (short*)w; w += (size_t)512 * 1024 * 2;
  short* wkvt = (short*)w; w += (size_t)128 * 1024 * 2;
  short* wot = (short*)w; w += (size_t)1024 * 512 * 2;
  short* q = (short*)w;   w += (size_t)16 * 2048 * 64 * 2;
  short* kb = (short*)w;  w += (size_t)2 * 2048 * 64 * 2;
  short* vt = (short*)w;  w += (size_t)2 * 64 * 2048 * 2;
  short* og = (short*)w;  w += (size_t)4096 * 512 * 2;
  float* vm = (float*)w;  w += 128 * 4;

  ln_cast_kernel<<<4096, 256, 0, stream>>>(x, gamma, xn, xb);
  wcast_t_kernel<<<dim3(8, 16), 256, 0, stream>>>(Wq, wqt, 1024, 512);
  wcast_t_kernel<<<dim3(2, 16), 256, 0, stream>>>(Wkv, wkvt, 1024, 128);
  wcast_t_kernel<<<dim3(16, 8), 256, 0, stream>>>(Wo, wot, 512, 1024);
  gemm_nt_kernel<0><<<dim3(4, 32), 256, 0, stream>>>(xn, wqt, q, nullptr, 4096, 512, 1024);
  gemm_nt_kernel<1><<<dim3(1, 32), 256, 0, stream>>>(xb, wkvt, kb, vt, 4096, 128, 1024);
  vmean_kernel<<<128, 256, 0, stream>>>(vt, vm);
  attn_kernel<<<dim3(8, 128), 128, 0, stream>>>(q, kb, vt, bias, mask, vm, og);
  gemm_nt_kernel<2><<<dim3(8, 32), 256, 0, stream>>>(og, wot, out, nullptr, 4096, 1024, 512);
}

// Round 13
// 137.115 us; speedup vs baseline: 1.4498x; 1.4498x over previous
//
#include <hip/hip_runtime.h>
#include <cfloat>
#include <cstdint>
#include <cstddef>

#define N_TOK 2048
#define D_MODEL 1024
#define N_HEAD 8
#define D_HEAD 64
#define N_BATCH 2
#define INNER_DIM 512

typedef __attribute__((ext_vector_type(4))) float f32x4;
typedef __bf16 bfv8 __attribute__((ext_vector_type(8)));

__device__ __forceinline__ short f2bf(float f) {
  union { float f; unsigned u; } x{f};
  unsigned r = (x.u + 0x7fffu + ((x.u >> 16) & 1u)) >> 16;
  return (short)r;
}
__device__ __forceinline__ float bf2f(short s) {
  union { unsigned u; float f; } x;
  x.u = ((unsigned)(unsigned short)s) << 16;
  return x.f;
}
__device__ __forceinline__ void gload_lds16(const void* g, void* l) {
  __builtin_amdgcn_global_load_lds(
      (const __attribute__((address_space(1))) void*)g,
      (__attribute__((address_space(3))) void*)l, 16, 0, 0);
}

// ---------------- LayerNorm + bf16 cast of both xn and x ----------------
__global__ __launch_bounds__(256) void ln_cast_kernel(
    const float* __restrict__ x, const float* __restrict__ gamma,
    short* __restrict__ xn, short* __restrict__ xb) {
  const int row = blockIdx.x;
  const int tid = threadIdx.x;
  const float4 v = ((const float4*)(x + (size_t)row * D_MODEL))[tid];
  float s = v.x + v.y + v.z + v.w;
  float s2 = v.x * v.x + v.y * v.y + v.z * v.z + v.w * v.w;
#pragma unroll
  for (int off = 1; off < 64; off <<= 1) {
    s += __shfl_xor(s, off);
    s2 += __shfl_xor(s2, off);
  }
  __shared__ float red[8];
  const int wid = tid >> 6;
  if ((tid & 63) == 0) { red[wid] = s; red[wid + 4] = s2; }
  __syncthreads();
  s = red[0] + red[1] + red[2] + red[3];
  s2 = red[4] + red[5] + red[6] + red[7];
  const float mu = s * (1.f / D_MODEL);
  const float var = s2 * (1.f / D_MODEL) - mu * mu;
  const float rstd = rsqrtf(var + 1e-5f);
  const float4 g = ((const float4*)gamma)[tid];
  short4 xnv, xbv;
  xnv.x = f2bf((v.x - mu) * rstd * g.x);
  xnv.y = f2bf((v.y - mu) * rstd * g.y);
  xnv.z = f2bf((v.z - mu) * rstd * g.z);
  xnv.w = f2bf((v.w - mu) * rstd * g.w);
  xbv.x = f2bf(v.x); xbv.y = f2bf(v.y); xbv.z = f2bf(v.z); xbv.w = f2bf(v.w);
  ((short4*)(xn + (size_t)row * D_MODEL))[tid] = xnv;
  ((short4*)(xb + (size_t)row * D_MODEL))[tid] = xbv;
}

// ---- all three weight cast+transpose in ONE launch (288 blocks of 64x64) ----
__global__ __launch_bounds__(256) void wcast_all_kernel(
    const float* __restrict__ Wq, const float* __restrict__ Wkv,
    const float* __restrict__ Wo, short* __restrict__ wqt,
    short* __restrict__ wkvt, short* __restrict__ wot) {
  const int bid = blockIdx.x;
  const float* W; short* Wt; int K, Nc, n0, k0;
  if (bid < 128) {        // Wq 1024x512: 8 n-tiles x 16 k-tiles
    W = Wq; Wt = wqt; K = 1024; Nc = 512;
    n0 = (bid & 7) * 64; k0 = (bid >> 3) * 64;
  } else if (bid < 160) { // Wkv 1024x128: 2 x 16
    const int t = bid - 128;
    W = Wkv; Wt = wkvt; K = 1024; Nc = 128;
    n0 = (t & 1) * 64; k0 = (t >> 1) * 64;
  } else {                // Wo 512x1024: 16 x 8
    const int t = bid - 160;
    W = Wo; Wt = wot; K = 512; Nc = 1024;
    n0 = (t & 15) * 64; k0 = (t >> 4) * 64;
  }
  __shared__ short t[64][65];
  const int tid = threadIdx.x;
#pragma unroll
  for (int i = 0; i < 16; ++i) {
    int lin = i * 256 + tid;
    int kr = lin >> 6, nc = lin & 63;
    t[nc][kr] = f2bf(W[(size_t)(k0 + kr) * Nc + n0 + nc]);
  }
  __syncthreads();
#pragma unroll
  for (int i = 0; i < 16; ++i) {
    int lin = i * 256 + tid;
    int nr = lin >> 6, kc = lin & 63;
    Wt[(size_t)(n0 + nr) * K + k0 + kc] = t[nr][kc];
  }
}

// ---- fused Q + KV projection GEMM: 128x64 tiles, 320 blocks (full coverage) ----
// gridDim.x = 10: x<8 -> Q tile (A=xn, B=wqt, N=512); x>=8 -> KV (A=xb, B=wkvt).
__global__ __launch_bounds__(256) void qkv_gemm_kernel(
    const short* __restrict__ xn, const short* __restrict__ xb,
    const short* __restrict__ wqt, const short* __restrict__ wkvt,
    short* __restrict__ q, short* __restrict__ kb, short* __restrict__ vt) {
  const bool isQ = blockIdx.x < 8;
  const short* A = isQ ? xn : xb;
  const short* Bt = isQ ? wqt : wkvt;
  const int n0 = (isQ ? blockIdx.x : (blockIdx.x - 8)) * 64;
  const int m0 = blockIdx.y * 128;
  const int K = 1024;
  __shared__ __align__(16) short As[128 * 64];
  __shared__ __align__(16) short Bs[64 * 64];
  const int tid = threadIdx.x;
  const int lane = tid & 63, wid = tid >> 6;
  const int l15 = lane & 15, l4 = lane >> 4;
  const int wr = wid * 32;  // wave's 32 output rows
  f32x4 acc[2][4] = {};
  for (int k0 = 0; k0 < K; k0 += 64) {
#pragma unroll
    for (int it = 0; it < 4; ++it) {
      int c = it * 256 + tid;
      int r = c >> 3, cc = (c & 7) << 3;
      gload_lds16(A + (size_t)(m0 + r) * K + k0 + cc, As + (size_t)(it * 256 + wid * 64) * 8);
    }
#pragma unroll
    for (int it = 0; it < 2; ++it) {
      int c = it * 256 + tid;
      int r = c >> 3, cc = (c & 7) << 3;
      gload_lds16(Bt + (size_t)(n0 + r) * K + k0 + cc, Bs + (size_t)(it * 256 + wid * 64) * 8);
    }
    __syncthreads();
#pragma unroll
    for (int kk = 0; kk < 2; ++kk) {
      bfv8 af[2], bfr[4];
#pragma unroll
      for (int i = 0; i < 2; ++i)
        af[i] = *(const bfv8*)&As[(wr + i * 16 + l15) * 64 + kk * 32 + l4 * 8];
#pragma unroll
      for (int i = 0; i < 4; ++i)
        bfr[i] = *(const bfv8*)&Bs[(i * 16 + l15) * 64 + kk * 32 + l4 * 8];
#pragma unroll
      for (int mi = 0; mi < 2; ++mi)
#pragma unroll
        for (int ni = 0; ni < 4; ++ni)
          acc[mi][ni] = __builtin_amdgcn_mfma_f32_16x16x32_bf16(af[mi], bfr[ni], acc[mi][ni], 0, 0, 0);
    }
    __syncthreads();
  }
#pragma unroll
  for (int mi = 0; mi < 2; ++mi) {
#pragma unroll
    for (int ni = 0; ni < 4; ++ni) {
#pragma unroll
      for (int r = 0; r < 4; ++r) {
        const int row = m0 + wr + mi * 16 + l4 * 4 + r;
        const int col = n0 + ni * 16 + l15;
        const float v = acc[mi][ni][r];
        const int b = row >> 11, n = row & (N_TOK - 1);
        if (isQ) {
          const int h = col >> 6, d = col & 63;
          q[(((size_t)(b * N_HEAD + h)) * N_TOK + n) * D_HEAD + d] = f2bf(v * 0.125f);
        } else {
          if (col < 64)
            kb[((size_t)b * N_TOK + n) * D_HEAD + col] = f2bf(v);
          else
            vt[((size_t)b * D_HEAD + (col - 64)) * N_TOK + n] = f2bf(v);
        }
      }
    }
  }
}

// ---------------- O-projection GEMM: 128x128 tile, fp32 out ----------------
__global__ __launch_bounds__(256) void ogemm_kernel(
    const short* __restrict__ A, const short* __restrict__ Bt,
    float* __restrict__ C, int M, int N, int K) {
  __shared__ __align__(16) short As[128 * 64];
  __shared__ __align__(16) short Bs[128 * 64];
  const int tid = threadIdx.x;
  const int lane = tid & 63, wid = tid >> 6;
  const int l15 = lane & 15, l4 = lane >> 4;
  const int m0 = blockIdx.y * 128, n0 = blockIdx.x * 128;
  const int wr = (wid >> 1) * 64, wc = (wid & 1) * 64;
  f32x4 acc[4][4] = {};
  for (int k0 = 0; k0 < K; k0 += 64) {
#pragma unroll
    for (int it = 0; it < 4; ++it) {
      int c = it * 256 + tid;
      int r = c >> 3, cc = (c & 7) << 3;
      gload_lds16(A + (size_t)(m0 + r) * K + k0 + cc, As + (size_t)(it * 256 + wid * 64) * 8);
      gload_lds16(Bt + (size_t)(n0 + r) * K + k0 + cc, Bs + (size_t)(it * 256 + wid * 64) * 8);
    }
    __syncthreads();
#pragma unroll
    for (int kk = 0; kk < 2; ++kk) {
      bfv8 af[4], bfr[4];
#pragma unroll
      for (int i = 0; i < 4; ++i) {
        af[i] = *(const bfv8*)&As[(wr + i * 16 + l15) * 64 + kk * 32 + l4 * 8];
        bfr[i] = *(const bfv8*)&Bs[(wc + i * 16 + l15) * 64 + kk * 32 + l4 * 8];
      }
#pragma unroll
      for (int mi = 0; mi < 4; ++mi)
#pragma unroll
        for (int ni = 0; ni < 4; ++ni)
          acc[mi][ni] = __builtin_amdgcn_mfma_f32_16x16x32_bf16(af[mi], bfr[ni], acc[mi][ni], 0, 0, 0);
    }
    __syncthreads();
  }
#pragma unroll
  for (int mi = 0; mi < 4; ++mi)
#pragma unroll
    for (int ni = 0; ni < 4; ++ni)
#pragma unroll
      for (int r = 0; r < 4; ++r) {
        const int row = m0 + wr + mi * 16 + l4 * 4 + r;
        const int col = n0 + wc + ni * 16 + l15;
        C[(size_t)row * N + col] = acc[mi][ni][r];
      }
}

// ---------------- column mean of V (for fully-masked rows) ----------------
__global__ __launch_bounds__(256) void vmean_kernel(const short* __restrict__ vt,
                                                    float* __restrict__ vm) {
  const int bd = blockIdx.x;  // b*64 + d
  const short* rowp = vt + (size_t)bd * N_TOK;
  const int tid = threadIdx.x;
  float s = 0.f;
  for (int i = tid; i < N_TOK; i += 256) s += bf2f(rowp[i]);
#pragma unroll
  for (int off = 1; off < 64; off <<= 1) s += __shfl_xor(s, off);
  __shared__ float red[4];
  if ((tid & 63) == 0) red[tid >> 6] = s;
  __syncthreads();
  if (tid == 0) vm[bd] = (red[0] + red[1] + red[2] + red[3]) * (1.f / N_TOK);
}

// ---------------- flash attention: R9 structure (1-wave blocks, reg bias ping-pong) ----------------
__global__ __launch_bounds__(64, 2) void attn_kernel(
    const short* __restrict__ qg,   // [B*H, N, 64] bf16, pre-scaled
    const short* __restrict__ kg,   // [B, N, 64] bf16
    const short* __restrict__ vtg,  // [B, 64, N] bf16 (transposed V)
    const float* __restrict__ bias, // [H, N, N] fp32
    const int* __restrict__ mask,   // [B, N] int
    const float* __restrict__ vm,   // [B, 64] fp32
    short* __restrict__ og) {       // [B*N, 512] bf16
  const int bh = blockIdx.x;            // 16
  const int qw = 127 - (int)blockIdx.y; // heavy-first
  const int b = bh >> 3, h = bh & 7;
  const int lane = threadIdx.x;
  const int l15 = lane & 15, l4 = lane >> 4;

  __shared__ __align__(16) short plds[1024];  // P staging [16x64] bf16, swizzled

  const int qrow0 = qw * 16;
  const short* qp = qg + ((size_t)bh * N_TOK + qrow0 + l15) * D_HEAD + l4 * 8;
  const bfv8 qf0 = *(const bfv8*)qp;
  const bfv8 qf1 = *(const bfv8*)(qp + 32);
  const int i_base = qrow0 + l4 * 4;
  const int nt = qw / 8 + 1;  // 128-wide j-tiles

  f32x4 oacc[4] = {};
  float m_r[4], l_r[4];
#pragma unroll
  for (int r = 0; r < 4; ++r) { m_r[r] = -FLT_MAX; l_r[r] = 0.f; }

  const float* bias_base = bias + ((size_t)h * N_TOK + i_base) * N_TOK + l15;
  const int* mask_b = mask + b * N_TOK + l15;

  float bX[32], bY[32];
#pragma unroll
  for (int mf = 0; mf < 8; ++mf)
#pragma unroll
    for (int r = 0; r < 4; ++r)
      bX[mf * 4 + r] = bias_base[(size_t)r * N_TOK + mf * 16];

  int t = 0;
#define BODY(BC, BN)                                                                    \
  {                                                                                     \
    const int j0 = t * 128;                                                             \
    int mk[8];                                                                          \
    _Pragma("unroll") for (int mf = 0; mf < 8; ++mf) mk[mf] = mask_b[j0 + mf * 16];     \
    bfv8 vf[16];                                                                        \
    const short* vp = vtg + ((size_t)b * D_HEAD + l15) * N_TOK + j0 + l4 * 8;           \
    _Pragma("unroll") for (int hh = 0; hh < 2; ++hh)                                    \
        _Pragma("unroll") for (int ks = 0; ks < 2; ++ks)                                \
            _Pragma("unroll") for (int df = 0; df < 4; ++df)                            \
                vf[hh * 8 + ks * 4 + df] =                                              \
                    *(const bfv8*)(vp + hh * 64 + df * (16 * N_TOK) + ks * 32);         \
    f32x4 s[8] = {};                                                                    \
    const short* kp = kg + ((size_t)b * N_TOK + j0 + l15) * D_HEAD + l4 * 8;            \
    _Pragma("unroll") for (int ks = 0; ks < 2; ++ks) {                                  \
      const bfv8 qf = ks ? qf1 : qf0;                                                   \
      _Pragma("unroll") for (int mf = 0; mf < 8; ++mf) {                                \
        const bfv8 kf = *(const bfv8*)(kp + mf * (16 * D_HEAD) + ks * 32);              \
        s[mf] = __builtin_amdgcn_mfma_f32_16x16x32_bf16(qf, kf, s[mf], 0, 0, 0);        \
      }                                                                                 \
    }                                                                                   \
    __builtin_amdgcn_sched_barrier(0);                                                  \
    {                                                                                   \
      const int jn = (t + 1 < nt) ? (t + 1) * 128 : j0;                                 \
      _Pragma("unroll") for (int mf = 0; mf < 8; ++mf)                                  \
          _Pragma("unroll") for (int r = 0; r < 4; ++r)                                 \
              BN[mf * 4 + r] = bias_base[(size_t)r * N_TOK + jn + mf * 16];             \
    }                                                                                   \
    __builtin_amdgcn_sched_barrier(0);                                                  \
    float rowmax[4] = {-FLT_MAX, -FLT_MAX, -FLT_MAX, -FLT_MAX};                         \
    _Pragma("unroll") for (int mf = 0; mf < 8; ++mf) {                                  \
      const int j = j0 + mf * 16 + l15;                                                 \
      _Pragma("unroll") for (int r = 0; r < 4; ++r) {                                   \
        float v = s[mf][r] + BC[mf * 4 + r];                                            \
        const bool ok = (j <= i_base + r) && (mk[mf] != 0);                             \
        v = ok ? v : -FLT_MAX;                                                          \
        s[mf][r] = v;                                                                   \
        rowmax[r] = fmaxf(rowmax[r], v);                                                \
      }                                                                                 \
    }                                                                                   \
    _Pragma("unroll") for (int off = 1; off < 16; off <<= 1)                            \
        _Pragma("unroll") for (int r = 0; r < 4; ++r)                                   \
            rowmax[r] = fmaxf(rowmax[r], __shfl_xor(rowmax[r], off));                   \
    float alpha[4], rsum[4];                                                            \
    _Pragma("unroll") for (int r = 0; r < 4; ++r) {                                     \
      const float mn = fmaxf(m_r[r], rowmax[r]);                                        \
      alpha[r] = __expf(m_r[r] - mn);                                                   \
      m_r[r] = mn;                                                                      \
      float rs = 0.f;                                                                   \
      _Pragma("unroll") for (int mf = 0; mf < 8; ++mf) {                                \
        const float e = __expf(s[mf][r] - mn);                                          \
        s[mf][r] = e;                                                                   \
        rs += e;                                                                        \
      }                                                                                 \
      rsum[r] = rs;                                                                     \
    }                                                                                   \
    _Pragma("unroll") for (int off = 1; off < 16; off <<= 1)                            \
        _Pragma("unroll") for (int r = 0; r < 4; ++r)                                   \
            rsum[r] += __shfl_xor(rsum[r], off);                                        \
    _Pragma("unroll") for (int r = 0; r < 4; ++r)                                       \
        l_r[r] = l_r[r] * alpha[r] + rsum[r];                                           \
    _Pragma("unroll") for (int df = 0; df < 4; ++df)                                    \
        _Pragma("unroll") for (int r = 0; r < 4; ++r)                                   \
            oacc[df][r] *= alpha[r];                                                    \
    _Pragma("unroll") for (int hh = 0; hh < 2; ++hh) {                                  \
      _Pragma("unroll") for (int nf = 0; nf < 4; ++nf) {                                \
        const int ch = (nf * 16 + l15) >> 3;                                            \
        const int cl = l15 & 7;                                                         \
        _Pragma("unroll") for (int r = 0; r < 4; ++r) {                                 \
          const int row = l4 * 4 + r;                                                   \
          const int g = row * 8 + (ch ^ (row & 7));                                     \
          plds[g * 8 + cl] = f2bf(s[hh * 4 + nf][r]);                                   \
        }                                                                               \
      }                                                                                 \
      _Pragma("unroll") for (int ks = 0; ks < 2; ++ks) {                                \
        const int g = l15 * 8 + ((ks * 4 + l4) ^ (l15 & 7));                            \
        const bfv8 pf = *(const bfv8*)&plds[g * 8];                                     \
        _Pragma("unroll") for (int df = 0; df < 4; ++df)                                \
          oacc[df] = __builtin_amdgcn_mfma_f32_16x16x32_bf16(                           \
              pf, vf[hh * 8 + ks * 4 + df], oacc[df], 0, 0, 0);                         \
      }                                                                                 \
    }                                                                                   \
    ++t;                                                                                \
  }

  while (t < nt) {
    BODY(bX, bY)
    if (t >= nt) break;
    BODY(bY, bX)
  }
#undef BODY

#pragma unroll
  for (int r = 0; r < 4; ++r) {
    const int i = i_base + r;
    const bool degen = (m_r[r] == -FLT_MAX);
    const float sc = degen ? 0.f : 1.f / l_r[r];
#pragma unroll
    for (int df = 0; df < 4; ++df) {
      const int d = df * 16 + l15;
      float v = oacc[df][r] * sc;
      if (degen) v = vm[b * D_HEAD + d];
      og[((size_t)b * N_TOK + i) * INNER_DIM + h * D_HEAD + d] = f2bf(v);
    }
  }
}

extern "C" void kernel_launch(void* const* d_in, const int* in_sizes, int n_in,
                              void* d_out, int out_size, void* d_ws, size_t ws_size,
                              hipStream_t stream) {
  const float* x = (const float*)d_in[0];
  const int* mask = (const int*)d_in[1];
  const float* bias = (const float*)d_in[2];
  const float* gamma = (const float*)d_in[3];
  const float* Wq = (const float*)d_in[4];
  const float* Wkv = (const float*)d_in[5];
  const float* Wo = (const float*)d_in[6];
  float* out = (float*)d_out;

  char* w = (char*)d_ws;
  short* xn = (short*)w;  w += (size_t)4096 * 1024 * 2;
  short* xb = (short*)w;  w += (size_t)4096 * 1024 * 2;
  short* wqt = (short*)w; w += (size_t)512 * 1024 * 2;
  short* wkvt = (short*)w; w += (size_t)128 * 1024 * 2;
  short* wot = (short*)w; w += (size_t)1024 * 512 * 2;
  short* q = (short*)w;   w += (size_t)16 * 2048 * 64 * 2;
  short* kb = (short*)w;  w += (size_t)2 * 2048 * 64 * 2;
  short* vt = (short*)w;  w += (size_t)2 * 64 * 2048 * 2;
  short* og = (short*)w;  w += (size_t)4096 * 512 * 2;
  float* vm = (float*)w;  w += 128 * 4;

  ln_cast_kernel<<<4096, 256, 0, stream>>>(x, gamma, xn, xb);
  wcast_all_kernel<<<288, 256, 0, stream>>>(Wq, Wkv, Wo, wqt, wkvt, wot);
  qkv_gemm_kernel<<<dim3(10, 32), 256, 0, stream>>>(xn, xb, wqt, wkvt, q, kb, vt);
  vmean_kernel<<<128, 256, 0, stream>>>(vt, vm);
  attn_kernel<<<dim3(16, 128), 64, 0, stream>>>(q, kb, vt, bias, mask, vm, og);
  ogemm_kernel<<<dim3(8, 32), 256, 0, stream>>>(og, wot, out, 4096, 1024, 512);
}